// Round 2
// baseline (112.415 us; speedup 1.0000x reference)
//
#include <hip/hip_runtime.h>

#define NG 512
#define NF 32
#define NP (96 * 96 * 16)   // 147456 points
#define TPB 256             // 4 waves; 64 points per block, 4 gaussian segments
#define PTS 64
#define NSEG 4
#define CPS 4               // chunks (of 32 gaussians) per segment

typedef _Float16 half8 __attribute__((ext_vector_type(8)));
typedef __fp16  fp16x2 __attribute__((ext_vector_type(2)));
typedef float f32x4 __attribute__((ext_vector_type(4)));
typedef unsigned uint4v __attribute__((ext_vector_type(4)));
typedef unsigned uint2v __attribute__((ext_vector_type(2)));

union H2U { fp16x2 h; unsigned u; };
union FRAG { unsigned u[4]; uint4v v; half8 h; };

__device__ __forceinline__ unsigned packh(__fp16 a, __fp16 b) {
    H2U p; p.h = (fp16x2){a, b}; return p.u;
}
__device__ __forceinline__ unsigned pkrtz(float a, float b) {
    H2U p; p.h = __builtin_amdgcn_cvt_pkrtz(a, b); return p.u;
}
// Swizzled dword index into a [256 rows][16 dw] LDS image (bank-balanced,
// 16B-aligned) — R7/R8/R9-verified.
__device__ __forceinline__ int ridx(int row, int grp) {
    return row * 16 + 4 * (grp ^ (row & 3));
}

// ---------------------------------------------------------------------------
// gr_pack (R7+-verified): blocks 0-1 psi A-frag image (hi/lo f16 split,
// MFMA A-operand order); blocks 2-33 feats B-frag image.
// ---------------------------------------------------------------------------
__global__ __launch_bounds__(256) void gr_pack(
    const float* __restrict__ means,
    const float* __restrict__ scales,
    const float* __restrict__ rots,
    const float* __restrict__ opac,
    const float* __restrict__ cam,
    const float* __restrict__ feats,
    unsigned* __restrict__ psi,
    unsigned* __restrict__ ftg)
{
    const int b = blockIdx.x;
    const int tid = threadIdx.x;

    if (b < 2) {
        const int n = b * 256 + tid;   // 0..511

        float mx = means[n * 3 + 0];
        float my = means[n * 3 + 1];
        float mz = means[n * 3 + 2];

        float h0 = cam[0]  * mx + cam[1]  * my + cam[2]  * mz + cam[3];
        float h1 = cam[4]  * mx + cam[5]  * my + cam[6]  * mz + cam[7];
        float h2 = cam[8]  * mx + cam[9]  * my + cam[10] * mz + cam[11];
        float h3 = cam[12] * mx + cam[13] * my + cam[14] * mz + cam[15];
        float ih3 = 1.0f / h3;
        mx = h0 * ih3; my = h1 * ih3; mz = h2 * ih3;

        float qw = rots[n * 4 + 0];
        float qx = rots[n * 4 + 1];
        float qy = rots[n * 4 + 2];
        float qz = rots[n * 4 + 3];
        float qinv = 1.0f / sqrtf(qw * qw + qx * qx + qy * qy + qz * qz);
        qw *= qinv; qx *= qinv; qy *= qinv; qz *= qinv;

        float R00 = 1.0f - 2.0f * (qy * qy + qz * qz);
        float R01 = 2.0f * (qx * qy - qw * qz);
        float R02 = 2.0f * (qx * qz + qw * qy);
        float R10 = 2.0f * (qx * qy + qw * qz);
        float R11 = 1.0f - 2.0f * (qx * qx + qz * qz);
        float R12 = 2.0f * (qy * qz - qw * qx);
        float R20 = 2.0f * (qx * qz - qw * qy);
        float R21 = 2.0f * (qy * qz + qw * qx);
        float R22 = 1.0f - 2.0f * (qx * qx + qy * qy);

        float s0 = scales[n * 3 + 0];
        float s1 = scales[n * 3 + 1];
        float s2 = scales[n * 3 + 2];
        const float es = 0.7213475204444817f;   // 0.5*log2(e)
        float i0 = es / (s0 * s0);
        float i1 = es / (s1 * s1);
        float i2 = es / (s2 * s2);

        float a00 = R00 * R00 * i0 + R01 * R01 * i1 + R02 * R02 * i2;
        float a01 = R00 * R10 * i0 + R01 * R11 * i1 + R02 * R12 * i2;
        float a02 = R00 * R20 * i0 + R01 * R21 * i1 + R02 * R22 * i2;
        float a11 = R10 * R10 * i0 + R11 * R11 * i1 + R12 * R12 * i2;
        float a12 = R10 * R20 * i0 + R11 * R21 * i1 + R12 * R22 * i2;
        float a22 = R20 * R20 * i0 + R21 * R21 * i1 + R22 * R22 * i2;

        float amx = a00 * mx + a01 * my + a02 * mz;
        float amy = a01 * mx + a11 * my + a12 * mz;
        float amz = a02 * mx + a12 * my + a22 * mz;

        float psv[10];
        psv[0] = -a00; psv[1] = -a11; psv[2] = -a22;
        psv[3] = -2.0f * a01; psv[4] = -2.0f * a02; psv[5] = -2.0f * a12;
        psv[6] = 2.0f * amx; psv[7] = 2.0f * amy; psv[8] = 2.0f * amz;
        psv[9] = __log2f(opac[n]) - (mx * amx + my * amy + mz * amz);

        __fp16 s[32];
#pragma unroll
        for (int i = 0; i < 10; ++i) {
            __fp16 hi = (__fp16)psv[i];
            __fp16 lo = (__fp16)(psv[i] - (float)hi);
            s[i] = hi; s[10 + i] = lo; s[20 + i] = hi;
        }
        s[30] = (__fp16)0.f; s[31] = (__fp16)0.f;

        unsigned* base = psi + (n >> 4) * 256;
        const int lr = n & 15;
#pragma unroll
        for (int q = 0; q < 4; ++q)
#pragma unroll
            for (int jp = 0; jp < 4; ++jp)
                base[(lr + 16 * q) * 4 + jp] = packh(s[8 * q + 2 * jp], s[8 * q + 2 * jp + 1]);
    } else {
        int d = (b - 2) * 256 + tid;   // 0..8191
        int c  = d >> 9;
        int r  = d & 511;
        int nt = r >> 8;
        int l  = (r >> 2) & 63;
        int jp = r & 3;
        int n  = nt * 16 + (l & 15);
        int k0 = c * 32 + (l >> 4) * 8 + 2 * jp;
        ftg[d] = pkrtz(feats[k0 * NF + n], feats[(k0 + 1) * NF + n]);
    }
}

// ---------------------------------------------------------------------------
// R11: chunk body factored out so the 4-chunk segment loop can be manually
// unrolled with TWO rotated psi-frag register sets — chunk c+1's pa0/pa1 are
// prefetched during chunk c's compute. Previously pa0 was consumed by the
// first Q-MFMA immediately after its load issued (zero vmcnt slack, ~200 cyc
// exposed L2 latency per chunk per wave). Now every frag has >= a full chunk
// (~500 cyc) of slack. bf0/bf1 keep their in-chunk issue (consumed after the
// T-chain, ~400 cyc slack — already covered). Compute is byte-identical to
// the R10-verified kernel.
// ---------------------------------------------------------------------------
__device__ __forceinline__ void gr_chunk(
    const unsigned* __restrict__ psi,
    const unsigned* __restrict__ ftg,
    unsigned* sh,
    int c, int cn, bool pf,
    int tid, int ln, int quad, int wv, int lane,
    const FRAG (&phif)[4], f32x4 (&pvacc)[4][2], float& T,
    FRAG& pa0, FRAG& pa1, FRAG& npa0, FRAG& npa1)
{
    // ---- VMEM: this chunk's B-frags + next chunk's A-frags, one issue burst
    FRAG bf0, bf1;
    bf0.v = ((const uint4v*)(ftg + c * 512 + 0))[lane];
    bf1.v = ((const uint4v*)(ftg + c * 512 + 256))[lane];
    if (pf) {
        npa0.v = ((const uint4v*)(psi + (2 * cn + 0) * 256))[lane];
        npa1.v = ((const uint4v*)(psi + (2 * cn + 1) * 256))[lane];
    }

    // ---- Q GEMM + exp2, m-tile at a time (caps live MFMA results).
    // pa0/pa1 were loaded one full chunk ago — no vmcnt stall here.
#pragma unroll
    for (int m = 0; m < 2; ++m) {
        const FRAG& pa = m ? pa1 : pa0;
        f32x4 qa[4];
#pragma unroll
        for (int nt = 0; nt < 4; ++nt)
            qa[nt] = __builtin_amdgcn_mfma_f32_16x16x32_f16(
                pa.h, phif[nt].h, (f32x4){0.f, 0.f, 0.f, 0.f}, 0, 0, 0);
#pragma unroll
        for (int nt = 0; nt < 4; ++nt) {
            float a0 = __builtin_amdgcn_exp2f(qa[nt][0]);
            float a1 = __builtin_amdgcn_exp2f(qa[nt][1]);
            float a2 = __builtin_amdgcn_exp2f(qa[nt][2]);
            float a3 = __builtin_amdgcn_exp2f(qa[nt][3]);
            const int row = wv * 64 + nt * 16 + ln;
            const int dbase = row * 16 + ((m * 8 + quad * 2) ^ (4 * (row & 3)));
            *(uint2v*)&sh[dbase] = (uint2v){pkrtz(a0, a1), pkrtz(a2, a3)};
        }
    }

    // ---- T-chain, quad-factored (R10-verified): cumulative (1-a) products
    // off the T critical path; only T *= p is serial (1 mul per 4 gaussians).
#pragma unroll
    for (int i = 0; i < 4; ++i) {
        uint4v a4 = *(const uint4v*)&sh[ridx(tid, i)];
        uint4v w4;
#pragma unroll
        for (int h = 0; h < 2; ++h) {
            H2U u0; u0.u = a4[2 * h + 0];
            H2U u1; u1.u = a4[2 * h + 1];
            float a0 = (float)u0.h[0];
            float a1 = (float)u0.h[1];
            float a2 = (float)u1.h[0];
            float a3 = (float)u1.h[1];
            float c1 = 1.0f - a0;
            float t1 = c1 * a1; float c2 = c1 - t1;
            float t2 = c2 * a2; float c3 = c2 - t2;
            float t3 = c3 * a3; float pq = c3 - t3;
            float w0 = T * a0;
            float w1 = T * t1;
            float w2 = T * t2;
            float w3 = T * t3;
            T = T * pq;
            w4[2 * h + 0] = pkrtz(w0, w1);
            w4[2 * h + 1] = pkrtz(w2, w3);
        }
        *(uint4v*)&sh[ridx(tid, i)] = w4;
    }

    // ---- PV GEMM (R6+-verified path)
#pragma unroll
    for (int mt = 0; mt < 4; ++mt) {
        FRAG af;
        af.v = *(const uint4v*)&sh[ridx(wv * 64 + mt * 16 + ln, quad)];
        pvacc[mt][0] = __builtin_amdgcn_mfma_f32_16x16x32_f16(af.h, bf0.h, pvacc[mt][0], 0, 0, 0);
        pvacc[mt][1] = __builtin_amdgcn_mfma_f32_16x16x32_f16(af.h, bf1.h, pvacc[mt][1], 0, 0, 0);
    }
}

// ---------------------------------------------------------------------------
// gr_render: 64 points/block, 4 waves = 4 gaussian segments of 128.
// R11: software-pipelined psi A-frag loads (see gr_chunk comment).
// ---------------------------------------------------------------------------
__global__ __launch_bounds__(256, 5) void gr_render(
    const unsigned* __restrict__ psi,
    const unsigned* __restrict__ ftg,
    const float* __restrict__ coords,
    float* __restrict__ out)
{
    __shared__ uint4v sh4[TPB * 4];          // 16 KB: [256 rows][16 dw]
    __shared__ float tT[NSEG][PTS];          // 1 KB: segment transmittances
    unsigned* sh = (unsigned*)sh4;

    const int tid  = threadIdx.x;
    const int ln   = tid & 15;
    const int quad = (tid >> 4) & 3;
    const int wv   = tid >> 6;
    const int lane = tid & 63;

    const int p = blockIdx.x * PTS + lane;   // this lane's point
    const float cx = coords[p * 3 + 0];
    const float cy = coords[p * 3 + 1];
    const float cz = coords[p * 3 + 2];

    // ---- prologue: issue chunk 0's A-frag loads; latency hides under the
    // phi' setup + LDS round-trip below.
    const int c0 = wv * CPS;
    FRAG paA0, paA1, paB0, paB1;
    paA0.v = ((const uint4v*)(psi + (2 * c0 + 0) * 256))[lane];
    paA1.v = ((const uint4v*)(psi + (2 * c0 + 1) * 256))[lane];

    // ---- phi' (hi/lo split) -> own wave's LDS rows -> B-frags (R7-verified)
    {
        float ph[10] = {cx * cx, cy * cy, cz * cz, cx * cy, cx * cz, cy * cz,
                        cx, cy, cz, 1.0f};
        __fp16 s[32];
#pragma unroll
        for (int i = 0; i < 10; ++i) {
            __fp16 hi = (__fp16)ph[i];
            __fp16 lo = (__fp16)(ph[i] - (float)hi);
            s[i] = hi; s[10 + i] = hi; s[20 + i] = lo;
        }
        s[30] = (__fp16)0.f; s[31] = (__fp16)0.f;
#pragma unroll
        for (int i = 0; i < 4; ++i) {
            uint4v v = (uint4v){packh(s[8 * i + 0], s[8 * i + 1]),
                                packh(s[8 * i + 2], s[8 * i + 3]),
                                packh(s[8 * i + 4], s[8 * i + 5]),
                                packh(s[8 * i + 6], s[8 * i + 7])};
            *(uint4v*)&sh[ridx(tid, i)] = v;
        }
    }

    FRAG phif[4];
#pragma unroll
    for (int nt = 0; nt < 4; ++nt)
        phif[nt].v = *(const uint4v*)&sh[ridx(wv * 64 + nt * 16 + ln, quad)];

    f32x4 pvacc[4][2];
#pragma unroll
    for (int mt = 0; mt < 4; ++mt) {
        pvacc[mt][0] = (f32x4){0.f, 0.f, 0.f, 0.f};
        pvacc[mt][1] = (f32x4){0.f, 0.f, 0.f, 0.f};
    }
    float T = 1.0f;

    // ---- 4 chunks, manually unrolled with rotated A-frag register sets
    gr_chunk(psi, ftg, sh, c0 + 0, c0 + 1, true,  tid, ln, quad, wv, lane,
             phif, pvacc, T, paA0, paA1, paB0, paB1);
    gr_chunk(psi, ftg, sh, c0 + 1, c0 + 2, true,  tid, ln, quad, wv, lane,
             phif, pvacc, T, paB0, paB1, paA0, paA1);
    gr_chunk(psi, ftg, sh, c0 + 2, c0 + 3, true,  tid, ln, quad, wv, lane,
             phif, pvacc, T, paA0, paA1, paB0, paB1);
    gr_chunk(psi, ftg, sh, c0 + 3, 0,      false, tid, ln, quad, wv, lane,
             phif, pvacc, T, paB0, paB1, paA0, paA1);

    // ---- write segment partials (f16 feature-pairs) into own rows; dword d
    // of row p holds features (d, d+16). |acc| <= max|feat| since sum(w)<=1.
    tT[wv][lane] = T;
#pragma unroll
    for (int mt = 0; mt < 4; ++mt)
#pragma unroll
        for (int r = 0; r < 4; ++r)
            sh[(wv * 64 + mt * 16 + quad * 4 + r) * 16 + ln] =
                pkrtz(pvacc[mt][0][r], pvacc[mt][1][r]);

    __syncthreads();

    // ---- compose segments: out = sum_s (prod_{s'<s} T_s') * acc_s
    {
        const int pp = tid >> 2;        // point 0..63
        const int g  = tid & 3;         // dword group (4 dwords)
        float t0 = tT[0][pp], t1 = tT[1][pp], t2 = tT[2][pp];
        float w1 = t0, w2 = t0 * t1, w3 = w2 * t2;

        float o[8];
        uint4v v0 = *(const uint4v*)&sh[(0 * 64 + pp) * 16 + g * 4];
#pragma unroll
        for (int j = 0; j < 4; ++j) {
            H2U u; u.u = v0[j];
            o[j] = (float)u.h[0]; o[4 + j] = (float)u.h[1];
        }
        uint4v v1 = *(const uint4v*)&sh[(1 * 64 + pp) * 16 + g * 4];
#pragma unroll
        for (int j = 0; j < 4; ++j) {
            H2U u; u.u = v1[j];
            o[j] = fmaf(w1, (float)u.h[0], o[j]);
            o[4 + j] = fmaf(w1, (float)u.h[1], o[4 + j]);
        }
        uint4v v2 = *(const uint4v*)&sh[(2 * 64 + pp) * 16 + g * 4];
#pragma unroll
        for (int j = 0; j < 4; ++j) {
            H2U u; u.u = v2[j];
            o[j] = fmaf(w2, (float)u.h[0], o[j]);
            o[4 + j] = fmaf(w2, (float)u.h[1], o[4 + j]);
        }
        uint4v v3 = *(const uint4v*)&sh[(3 * 64 + pp) * 16 + g * 4];
#pragma unroll
        for (int j = 0; j < 4; ++j) {
            H2U u; u.u = v3[j];
            o[j] = fmaf(w3, (float)u.h[0], o[j]);
            o[4 + j] = fmaf(w3, (float)u.h[1], o[4 + j]);
        }

        float* __restrict__ ob = out + (blockIdx.x * PTS + pp) * NF + g * 4;
        *(float4*)ob        = make_float4(o[0], o[1], o[2], o[3]);
        *(float4*)(ob + 16) = make_float4(o[4], o[5], o[6], o[7]);
    }
}

extern "C" void kernel_launch(void* const* d_in, const int* in_sizes, int n_in,
                              void* d_out, int out_size, void* d_ws, size_t ws_size,
                              hipStream_t stream)
{
    const float* means  = (const float*)d_in[0];   // (512,3)
    const float* scales = (const float*)d_in[1];   // (512,3)
    const float* rots   = (const float*)d_in[2];   // (512,4)
    const float* opac   = (const float*)d_in[3];   // (512,1)
    const float* feats  = (const float*)d_in[4];   // (512,32)
    const float* cam    = (const float*)d_in[5];   // (4,4)
    const float* coords = (const float*)d_in[6];   // (96,96,16,3)
    float* out = (float*)d_out;                    // (96,96,16,32) fp32

    unsigned* psi = (unsigned*)d_ws;               // 32 KiB: gaussian A-frag image
    unsigned* ftg = psi + 32 * 256;                // 32 KiB: feats B-frag image

    gr_pack<<<34, 256, 0, stream>>>(means, scales, rots, opac, cam, feats, psi, ftg);
    gr_render<<<NP / PTS, TPB, 0, stream>>>(psi, ftg, coords, out);
}

// Round 4
// 105.844 us; speedup vs baseline: 1.0621x; 1.0621x over previous
//
#include <hip/hip_runtime.h>

#define NG 512
#define NF 32
#define NP (96 * 96 * 16)   // 147456 points
#define TPB 256             // 4 waves; 64 points per block, 4 gaussian segments
#define PTS 64
#define NSEG 4
#define CPS 4               // chunks (of 32 gaussians) per segment
#define RSTR 20             // R12: LDS row stride in dwords (80 B). 5 coprime
                            // to 8 -> bank base 4*((5*row+grp)%8) spreads all
                            // 32 banks; old stride 16 locked each access to
                            // 16 banks (2-way conflict on every b128).

typedef _Float16 half8 __attribute__((ext_vector_type(8)));
typedef __fp16  fp16x2 __attribute__((ext_vector_type(2)));
typedef float f32x4 __attribute__((ext_vector_type(4)));
typedef unsigned uint4v __attribute__((ext_vector_type(4)));
typedef unsigned uint2v __attribute__((ext_vector_type(2)));

union H2U { fp16x2 h; unsigned u; };
union FRAG { unsigned u[4]; uint4v v; half8 h; };

__device__ __forceinline__ unsigned packh(__fp16 a, __fp16 b) {
    H2U p; p.h = (fp16x2){a, b}; return p.u;
}
__device__ __forceinline__ unsigned pkrtz(float a, float b) {
    H2U p; p.h = __builtin_amdgcn_cvt_pkrtz(a, b); return p.u;
}
// R12: dword index into a [256 rows][20 dw] LDS image. In-row layout is
// LINEAR (group j at dword 4j); bank spreading comes from the stride-20 row
// rotation. Conflict-analysis (all verified by hand):
//   own-row b128 (phi/T-chain): 8 dwords/bank  = ideal
//   phif/PV b128 (quads share row): 8/bank     = ideal
//   exp2 b64 store: 4/bank                     = ideal
//   epilogue b32 store: 2-way (was 4-way)      ~ free (m136)
//   compose b128: 8/bank                       = ideal
__device__ __forceinline__ int ridx(int row, int grp) {
    return row * RSTR + 4 * grp;
}

// ---------------------------------------------------------------------------
// gr_pack (R7+-verified): blocks 0-1 psi A-frag image (hi/lo f16 split,
// MFMA A-operand order); blocks 2-33 feats B-frag image. (Global images —
// unchanged by the R12 LDS relayout.)
// ---------------------------------------------------------------------------
__global__ __launch_bounds__(256) void gr_pack(
    const float* __restrict__ means,
    const float* __restrict__ scales,
    const float* __restrict__ rots,
    const float* __restrict__ opac,
    const float* __restrict__ cam,
    const float* __restrict__ feats,
    unsigned* __restrict__ psi,
    unsigned* __restrict__ ftg)
{
    const int b = blockIdx.x;
    const int tid = threadIdx.x;

    if (b < 2) {
        const int n = b * 256 + tid;   // 0..511

        float mx = means[n * 3 + 0];
        float my = means[n * 3 + 1];
        float mz = means[n * 3 + 2];

        float h0 = cam[0]  * mx + cam[1]  * my + cam[2]  * mz + cam[3];
        float h1 = cam[4]  * mx + cam[5]  * my + cam[6]  * mz + cam[7];
        float h2 = cam[8]  * mx + cam[9]  * my + cam[10] * mz + cam[11];
        float h3 = cam[12] * mx + cam[13] * my + cam[14] * mz + cam[15];
        float ih3 = 1.0f / h3;
        mx = h0 * ih3; my = h1 * ih3; mz = h2 * ih3;

        float qw = rots[n * 4 + 0];
        float qx = rots[n * 4 + 1];
        float qy = rots[n * 4 + 2];
        float qz = rots[n * 4 + 3];
        float qinv = 1.0f / sqrtf(qw * qw + qx * qx + qy * qy + qz * qz);
        qw *= qinv; qx *= qinv; qy *= qinv; qz *= qinv;

        float R00 = 1.0f - 2.0f * (qy * qy + qz * qz);
        float R01 = 2.0f * (qx * qy - qw * qz);
        float R02 = 2.0f * (qx * qz + qw * qy);
        float R10 = 2.0f * (qx * qy + qw * qz);
        float R11 = 1.0f - 2.0f * (qx * qx + qz * qz);
        float R12 = 2.0f * (qy * qz - qw * qx);
        float R20 = 2.0f * (qx * qz - qw * qy);
        float R21 = 2.0f * (qy * qz + qw * qx);
        float R22 = 1.0f - 2.0f * (qx * qx + qy * qy);

        float s0 = scales[n * 3 + 0];
        float s1 = scales[n * 3 + 1];
        float s2 = scales[n * 3 + 2];
        const float es = 0.7213475204444817f;   // 0.5*log2(e)
        float i0 = es / (s0 * s0);
        float i1 = es / (s1 * s1);
        float i2 = es / (s2 * s2);

        float a00 = R00 * R00 * i0 + R01 * R01 * i1 + R02 * R02 * i2;
        float a01 = R00 * R10 * i0 + R01 * R11 * i1 + R02 * R12 * i2;
        float a02 = R00 * R20 * i0 + R01 * R21 * i1 + R02 * R22 * i2;
        float a11 = R10 * R10 * i0 + R11 * R11 * i1 + R12 * R12 * i2;
        float a12 = R10 * R20 * i0 + R11 * R21 * i1 + R12 * R22 * i2;
        float a22 = R20 * R20 * i0 + R21 * R21 * i1 + R22 * R22 * i2;

        float amx = a00 * mx + a01 * my + a02 * mz;
        float amy = a01 * mx + a11 * my + a12 * mz;
        float amz = a02 * mx + a12 * my + a22 * mz;

        float psv[10];
        psv[0] = -a00; psv[1] = -a11; psv[2] = -a22;
        psv[3] = -2.0f * a01; psv[4] = -2.0f * a02; psv[5] = -2.0f * a12;
        psv[6] = 2.0f * amx; psv[7] = 2.0f * amy; psv[8] = 2.0f * amz;
        psv[9] = __log2f(opac[n]) - (mx * amx + my * amy + mz * amz);

        __fp16 s[32];
#pragma unroll
        for (int i = 0; i < 10; ++i) {
            __fp16 hi = (__fp16)psv[i];
            __fp16 lo = (__fp16)(psv[i] - (float)hi);
            s[i] = hi; s[10 + i] = lo; s[20 + i] = hi;
        }
        s[30] = (__fp16)0.f; s[31] = (__fp16)0.f;

        unsigned* base = psi + (n >> 4) * 256;
        const int lr = n & 15;
#pragma unroll
        for (int q = 0; q < 4; ++q)
#pragma unroll
            for (int jp = 0; jp < 4; ++jp)
                base[(lr + 16 * q) * 4 + jp] = packh(s[8 * q + 2 * jp], s[8 * q + 2 * jp + 1]);
    } else {
        int d = (b - 2) * 256 + tid;   // 0..8191
        int c  = d >> 9;
        int r  = d & 511;
        int nt = r >> 8;
        int l  = (r >> 2) & 63;
        int jp = r & 3;
        int n  = nt * 16 + (l & 15);
        int k0 = c * 32 + (l >> 4) * 8 + 2 * jp;
        ftg[d] = pkrtz(feats[k0 * NF + n], feats[(k0 + 1) * NF + n]);
    }
}

// ---------------------------------------------------------------------------
// R11: chunk body with rotated psi-frag register sets (pa prefetched a full
// chunk ahead). R12: all LDS indexing via the stride-20 linear layout; the
// exp2 store slot and T-chain/PV read slot permutations changed TOGETHER
// (both identity now), so numerics are bit-identical to R10/R11.
// ---------------------------------------------------------------------------
__device__ __forceinline__ void gr_chunk(
    const unsigned* __restrict__ psi,
    const unsigned* __restrict__ ftg,
    unsigned* sh,
    int c, int cn, bool pf,
    int tid, int ln, int quad, int wv, int lane,
    const FRAG (&phif)[4], f32x4 (&pvacc)[4][2], float& T,
    FRAG& pa0, FRAG& pa1, FRAG& npa0, FRAG& npa1)
{
    // ---- VMEM: this chunk's B-frags + next chunk's A-frags, one issue burst
    FRAG bf0, bf1;
    bf0.v = ((const uint4v*)(ftg + c * 512 + 0))[lane];
    bf1.v = ((const uint4v*)(ftg + c * 512 + 256))[lane];
    if (pf) {
        npa0.v = ((const uint4v*)(psi + (2 * cn + 0) * 256))[lane];
        npa1.v = ((const uint4v*)(psi + (2 * cn + 1) * 256))[lane];
    }

    // ---- Q GEMM + exp2, m-tile at a time (caps live MFMA results).
#pragma unroll
    for (int m = 0; m < 2; ++m) {
        const FRAG& pa = m ? pa1 : pa0;
        f32x4 qa[4];
#pragma unroll
        for (int nt = 0; nt < 4; ++nt)
            qa[nt] = __builtin_amdgcn_mfma_f32_16x16x32_f16(
                pa.h, phif[nt].h, (f32x4){0.f, 0.f, 0.f, 0.f}, 0, 0, 0);
#pragma unroll
        for (int nt = 0; nt < 4; ++nt) {
            float a0 = __builtin_amdgcn_exp2f(qa[nt][0]);
            float a1 = __builtin_amdgcn_exp2f(qa[nt][1]);
            float a2 = __builtin_amdgcn_exp2f(qa[nt][2]);
            float a3 = __builtin_amdgcn_exp2f(qa[nt][3]);
            const int row = wv * 64 + nt * 16 + ln;
            // R12: linear slot (m*8 + quad*2); bank spread via row*RSTR.
            const int dbase = row * RSTR + (m * 8 + quad * 2);
            *(uint2v*)&sh[dbase] = (uint2v){pkrtz(a0, a1), pkrtz(a2, a3)};
        }
    }

    // ---- T-chain, quad-factored (R10-verified): cumulative (1-a) products
    // off the T critical path; only T *= p is serial (1 mul per 4 gaussians).
#pragma unroll
    for (int i = 0; i < 4; ++i) {
        uint4v a4 = *(const uint4v*)&sh[ridx(tid, i)];
        uint4v w4;
#pragma unroll
        for (int h = 0; h < 2; ++h) {
            H2U u0; u0.u = a4[2 * h + 0];
            H2U u1; u1.u = a4[2 * h + 1];
            float a0 = (float)u0.h[0];
            float a1 = (float)u0.h[1];
            float a2 = (float)u1.h[0];
            float a3 = (float)u1.h[1];
            float c1 = 1.0f - a0;
            float t1 = c1 * a1; float c2 = c1 - t1;
            float t2 = c2 * a2; float c3 = c2 - t2;
            float t3 = c3 * a3; float pq = c3 - t3;
            float w0 = T * a0;
            float w1 = T * t1;
            float w2 = T * t2;
            float w3 = T * t3;
            T = T * pq;
            w4[2 * h + 0] = pkrtz(w0, w1);
            w4[2 * h + 1] = pkrtz(w2, w3);
        }
        *(uint4v*)&sh[ridx(tid, i)] = w4;
    }

    // ---- PV GEMM (R6+-verified path)
#pragma unroll
    for (int mt = 0; mt < 4; ++mt) {
        FRAG af;
        af.v = *(const uint4v*)&sh[ridx(wv * 64 + mt * 16 + ln, quad)];
        pvacc[mt][0] = __builtin_amdgcn_mfma_f32_16x16x32_f16(af.h, bf0.h, pvacc[mt][0], 0, 0, 0);
        pvacc[mt][1] = __builtin_amdgcn_mfma_f32_16x16x32_f16(af.h, bf1.h, pvacc[mt][1], 0, 0, 0);
    }
}

// ---------------------------------------------------------------------------
// gr_render: 64 points/block, 4 waves = 4 gaussian segments of 128.
// R11: software-pipelined psi A-frag loads. R12: stride-20 conflict-free LDS.
// ---------------------------------------------------------------------------
__global__ __launch_bounds__(256, 5) void gr_render(
    const unsigned* __restrict__ psi,
    const unsigned* __restrict__ ftg,
    const float* __restrict__ coords,
    float* __restrict__ out)
{
    __shared__ uint4v sh4[TPB * 5];          // 20 KB: [256 rows][20 dw]
    __shared__ float tT[NSEG][PTS];          // 1 KB: segment transmittances
    unsigned* sh = (unsigned*)sh4;

    const int tid  = threadIdx.x;
    const int ln   = tid & 15;
    const int quad = (tid >> 4) & 3;
    const int wv   = tid >> 6;
    const int lane = tid & 63;

    const int p = blockIdx.x * PTS + lane;   // this lane's point
    const float cx = coords[p * 3 + 0];
    const float cy = coords[p * 3 + 1];
    const float cz = coords[p * 3 + 2];

    // ---- prologue: issue chunk 0's A-frag loads; latency hides under the
    // phi' setup + LDS round-trip below.
    const int c0 = wv * CPS;
    FRAG paA0, paA1, paB0, paB1;
    paA0.v = ((const uint4v*)(psi + (2 * c0 + 0) * 256))[lane];
    paA1.v = ((const uint4v*)(psi + (2 * c0 + 1) * 256))[lane];

    // ---- phi' (hi/lo split) -> own wave's LDS rows -> B-frags (R7-verified)
    {
        float ph[10] = {cx * cx, cy * cy, cz * cz, cx * cy, cx * cz, cy * cz,
                        cx, cy, cz, 1.0f};
        __fp16 s[32];
#pragma unroll
        for (int i = 0; i < 10; ++i) {
            __fp16 hi = (__fp16)ph[i];
            __fp16 lo = (__fp16)(ph[i] - (float)hi);
            s[i] = hi; s[10 + i] = hi; s[20 + i] = lo;
        }
        s[30] = (__fp16)0.f; s[31] = (__fp16)0.f;
#pragma unroll
        for (int i = 0; i < 4; ++i) {
            uint4v v = (uint4v){packh(s[8 * i + 0], s[8 * i + 1]),
                                packh(s[8 * i + 2], s[8 * i + 3]),
                                packh(s[8 * i + 4], s[8 * i + 5]),
                                packh(s[8 * i + 6], s[8 * i + 7])};
            *(uint4v*)&sh[ridx(tid, i)] = v;
        }
    }

    FRAG phif[4];
#pragma unroll
    for (int nt = 0; nt < 4; ++nt)
        phif[nt].v = *(const uint4v*)&sh[ridx(wv * 64 + nt * 16 + ln, quad)];

    f32x4 pvacc[4][2];
#pragma unroll
    for (int mt = 0; mt < 4; ++mt) {
        pvacc[mt][0] = (f32x4){0.f, 0.f, 0.f, 0.f};
        pvacc[mt][1] = (f32x4){0.f, 0.f, 0.f, 0.f};
    }
    float T = 1.0f;

    // ---- 4 chunks, manually unrolled with rotated A-frag register sets
    gr_chunk(psi, ftg, sh, c0 + 0, c0 + 1, true,  tid, ln, quad, wv, lane,
             phif, pvacc, T, paA0, paA1, paB0, paB1);
    gr_chunk(psi, ftg, sh, c0 + 1, c0 + 2, true,  tid, ln, quad, wv, lane,
             phif, pvacc, T, paB0, paB1, paA0, paA1);
    gr_chunk(psi, ftg, sh, c0 + 2, c0 + 3, true,  tid, ln, quad, wv, lane,
             phif, pvacc, T, paA0, paA1, paB0, paB1);
    gr_chunk(psi, ftg, sh, c0 + 3, 0,      false, tid, ln, quad, wv, lane,
             phif, pvacc, T, paB0, paB1, paA0, paA1);

    // ---- write segment partials (f16 feature-pairs) into own rows; dword d
    // of row p holds features (d, d+16). |acc| <= max|feat| since sum(w)<=1.
    tT[wv][lane] = T;
#pragma unroll
    for (int mt = 0; mt < 4; ++mt)
#pragma unroll
        for (int r = 0; r < 4; ++r)
            sh[(wv * 64 + mt * 16 + quad * 4 + r) * RSTR + ln] =
                pkrtz(pvacc[mt][0][r], pvacc[mt][1][r]);

    __syncthreads();

    // ---- compose segments: out = sum_s (prod_{s'<s} T_s') * acc_s
    {
        const int pp = tid >> 2;        // point 0..63
        const int g  = tid & 3;         // dword group (4 dwords)
        float t0 = tT[0][pp], t1 = tT[1][pp], t2 = tT[2][pp];
        float w1 = t0, w2 = t0 * t1, w3 = w2 * t2;

        float o[8];
        uint4v v0 = *(const uint4v*)&sh[(0 * 64 + pp) * RSTR + g * 4];
#pragma unroll
        for (int j = 0; j < 4; ++j) {
            H2U u; u.u = v0[j];
            o[j] = (float)u.h[0]; o[4 + j] = (float)u.h[1];
        }
        uint4v v1 = *(const uint4v*)&sh[(1 * 64 + pp) * RSTR + g * 4];
#pragma unroll
        for (int j = 0; j < 4; ++j) {
            H2U u; u.u = v1[j];
            o[j] = fmaf(w1, (float)u.h[0], o[j]);
            o[4 + j] = fmaf(w1, (float)u.h[1], o[4 + j]);
        }
        uint4v v2 = *(const uint4v*)&sh[(2 * 64 + pp) * RSTR + g * 4];
#pragma unroll
        for (int j = 0; j < 4; ++j) {
            H2U u; u.u = v2[j];
            o[j] = fmaf(w2, (float)u.h[0], o[j]);
            o[4 + j] = fmaf(w2, (float)u.h[1], o[4 + j]);
        }
        uint4v v3 = *(const uint4v*)&sh[(3 * 64 + pp) * RSTR + g * 4];
#pragma unroll
        for (int j = 0; j < 4; ++j) {
            H2U u; u.u = v3[j];
            o[j] = fmaf(w3, (float)u.h[0], o[j]);
            o[4 + j] = fmaf(w3, (float)u.h[1], o[4 + j]);
        }

        float* __restrict__ ob = out + (blockIdx.x * PTS + pp) * NF + g * 4;
        *(float4*)ob        = make_float4(o[0], o[1], o[2], o[3]);
        *(float4*)(ob + 16) = make_float4(o[4], o[5], o[6], o[7]);
    }
}

extern "C" void kernel_launch(void* const* d_in, const int* in_sizes, int n_in,
                              void* d_out, int out_size, void* d_ws, size_t ws_size,
                              hipStream_t stream)
{
    const float* means  = (const float*)d_in[0];   // (512,3)
    const float* scales = (const float*)d_in[1];   // (512,3)
    const float* rots   = (const float*)d_in[2];   // (512,4)
    const float* opac   = (const float*)d_in[3];   // (512,1)
    const float* feats  = (const float*)d_in[4];   // (512,32)
    const float* cam    = (const float*)d_in[5];   // (4,4)
    const float* coords = (const float*)d_in[6];   // (96,96,16,3)
    float* out = (float*)d_out;                    // (96,96,16,32) fp32

    unsigned* psi = (unsigned*)d_ws;               // 32 KiB: gaussian A-frag image
    unsigned* ftg = psi + 32 * 256;                // 32 KiB: feats B-frag image

    gr_pack<<<34, 256, 0, stream>>>(means, scales, rots, opac, cam, feats, psi, ftg);
    gr_render<<<NP / PTS, TPB, 0, stream>>>(psi, ftg, coords, out);
}

// Round 5
// 96.457 us; speedup vs baseline: 1.1654x; 1.0973x over previous
//
#include <hip/hip_runtime.h>

#define NG 512
#define NF 32
#define NP (96 * 96 * 16)   // 147456 points
#define TPB 512             // R13: 8 waves; 64 points per block, 8 gaussian segments
#define PTS 64
#define NSEG 8
#define CPS 2               // chunks (of 32 gaussians) per segment
#define RSTR 20             // R12: LDS row stride in dwords (80 B). 5 coprime
                            // to 8 -> bank base 4*((5*row+grp)%8) spreads all
                            // 32 banks (stride 16 locked b128s to 16 banks).

typedef _Float16 half8 __attribute__((ext_vector_type(8)));
typedef __fp16  fp16x2 __attribute__((ext_vector_type(2)));
typedef float f32x4 __attribute__((ext_vector_type(4)));
typedef unsigned uint4v __attribute__((ext_vector_type(4)));
typedef unsigned uint2v __attribute__((ext_vector_type(2)));

union H2U { fp16x2 h; unsigned u; };
union FRAG { unsigned u[4]; uint4v v; half8 h; };

__device__ __forceinline__ unsigned packh(__fp16 a, __fp16 b) {
    H2U p; p.h = (fp16x2){a, b}; return p.u;
}
__device__ __forceinline__ unsigned pkrtz(float a, float b) {
    H2U p; p.h = __builtin_amdgcn_cvt_pkrtz(a, b); return p.u;
}
// R12: dword index into a [512 rows][20 dw] LDS image, linear in-row slots.
// Dwords 0..15 hold frag data; dword 16 holds the segment transmittance
// (R13: tT folded here so block LDS = 512*80 B = 40960 -> 4 blocks/CU exactly).
__device__ __forceinline__ int ridx(int row, int grp) {
    return row * RSTR + 4 * grp;
}

// ---------------------------------------------------------------------------
// gr_pack (R7+-verified): blocks 0-1 psi A-frag image (hi/lo f16 split,
// MFMA A-operand order); blocks 2-33 feats B-frag image. (Unchanged.)
// ---------------------------------------------------------------------------
__global__ __launch_bounds__(256) void gr_pack(
    const float* __restrict__ means,
    const float* __restrict__ scales,
    const float* __restrict__ rots,
    const float* __restrict__ opac,
    const float* __restrict__ cam,
    const float* __restrict__ feats,
    unsigned* __restrict__ psi,
    unsigned* __restrict__ ftg)
{
    const int b = blockIdx.x;
    const int tid = threadIdx.x;

    if (b < 2) {
        const int n = b * 256 + tid;   // 0..511

        float mx = means[n * 3 + 0];
        float my = means[n * 3 + 1];
        float mz = means[n * 3 + 2];

        float h0 = cam[0]  * mx + cam[1]  * my + cam[2]  * mz + cam[3];
        float h1 = cam[4]  * mx + cam[5]  * my + cam[6]  * mz + cam[7];
        float h2 = cam[8]  * mx + cam[9]  * my + cam[10] * mz + cam[11];
        float h3 = cam[12] * mx + cam[13] * my + cam[14] * mz + cam[15];
        float ih3 = 1.0f / h3;
        mx = h0 * ih3; my = h1 * ih3; mz = h2 * ih3;

        float qw = rots[n * 4 + 0];
        float qx = rots[n * 4 + 1];
        float qy = rots[n * 4 + 2];
        float qz = rots[n * 4 + 3];
        float qinv = 1.0f / sqrtf(qw * qw + qx * qx + qy * qy + qz * qz);
        qw *= qinv; qx *= qinv; qy *= qinv; qz *= qinv;

        float R00 = 1.0f - 2.0f * (qy * qy + qz * qz);
        float R01 = 2.0f * (qx * qy - qw * qz);
        float R02 = 2.0f * (qx * qz + qw * qy);
        float R10 = 2.0f * (qx * qy + qw * qz);
        float R11 = 1.0f - 2.0f * (qx * qx + qz * qz);
        float R12 = 2.0f * (qy * qz - qw * qx);
        float R20 = 2.0f * (qx * qz - qw * qy);
        float R21 = 2.0f * (qy * qz + qw * qx);
        float R22 = 1.0f - 2.0f * (qx * qx + qy * qy);

        float s0 = scales[n * 3 + 0];
        float s1 = scales[n * 3 + 1];
        float s2 = scales[n * 3 + 2];
        const float es = 0.7213475204444817f;   // 0.5*log2(e)
        float i0 = es / (s0 * s0);
        float i1 = es / (s1 * s1);
        float i2 = es / (s2 * s2);

        float a00 = R00 * R00 * i0 + R01 * R01 * i1 + R02 * R02 * i2;
        float a01 = R00 * R10 * i0 + R01 * R11 * i1 + R02 * R12 * i2;
        float a02 = R00 * R20 * i0 + R01 * R21 * i1 + R02 * R22 * i2;
        float a11 = R10 * R10 * i0 + R11 * R11 * i1 + R12 * R12 * i2;
        float a12 = R10 * R20 * i0 + R11 * R21 * i1 + R12 * R22 * i2;
        float a22 = R20 * R20 * i0 + R21 * R21 * i1 + R22 * R22 * i2;

        float amx = a00 * mx + a01 * my + a02 * mz;
        float amy = a01 * mx + a11 * my + a12 * mz;
        float amz = a02 * mx + a12 * my + a22 * mz;

        float psv[10];
        psv[0] = -a00; psv[1] = -a11; psv[2] = -a22;
        psv[3] = -2.0f * a01; psv[4] = -2.0f * a02; psv[5] = -2.0f * a12;
        psv[6] = 2.0f * amx; psv[7] = 2.0f * amy; psv[8] = 2.0f * amz;
        psv[9] = __log2f(opac[n]) - (mx * amx + my * amy + mz * amz);

        __fp16 s[32];
#pragma unroll
        for (int i = 0; i < 10; ++i) {
            __fp16 hi = (__fp16)psv[i];
            __fp16 lo = (__fp16)(psv[i] - (float)hi);
            s[i] = hi; s[10 + i] = lo; s[20 + i] = hi;
        }
        s[30] = (__fp16)0.f; s[31] = (__fp16)0.f;

        unsigned* base = psi + (n >> 4) * 256;
        const int lr = n & 15;
#pragma unroll
        for (int q = 0; q < 4; ++q)
#pragma unroll
            for (int jp = 0; jp < 4; ++jp)
                base[(lr + 16 * q) * 4 + jp] = packh(s[8 * q + 2 * jp], s[8 * q + 2 * jp + 1]);
    } else {
        int d = (b - 2) * 256 + tid;   // 0..8191
        int c  = d >> 9;
        int r  = d & 511;
        int nt = r >> 8;
        int l  = (r >> 2) & 63;
        int jp = r & 3;
        int n  = nt * 16 + (l & 15);
        int k0 = c * 32 + (l >> 4) * 8 + 2 * jp;
        ftg[d] = pkrtz(feats[k0 * NF + n], feats[(k0 + 1) * NF + n]);
    }
}

// ---------------------------------------------------------------------------
// Chunk body (R10/R11/R12-verified math, bit-identical). R11 pipeline:
// next chunk's psi A-frags prefetched during this chunk's compute.
// ---------------------------------------------------------------------------
__device__ __forceinline__ void gr_chunk(
    const unsigned* __restrict__ psi,
    const unsigned* __restrict__ ftg,
    unsigned* sh,
    int c, int cn, bool pf,
    int tid, int ln, int quad, int wv, int lane,
    const FRAG (&phif)[4], f32x4 (&pvacc)[4][2], float& T,
    FRAG& pa0, FRAG& pa1, FRAG& npa0, FRAG& npa1)
{
    // ---- VMEM: this chunk's B-frags + next chunk's A-frags, one issue burst
    FRAG bf0, bf1;
    bf0.v = ((const uint4v*)(ftg + c * 512 + 0))[lane];
    bf1.v = ((const uint4v*)(ftg + c * 512 + 256))[lane];
    if (pf) {
        npa0.v = ((const uint4v*)(psi + (2 * cn + 0) * 256))[lane];
        npa1.v = ((const uint4v*)(psi + (2 * cn + 1) * 256))[lane];
    }

    // ---- Q GEMM + exp2, m-tile at a time (caps live MFMA results).
#pragma unroll
    for (int m = 0; m < 2; ++m) {
        const FRAG& pa = m ? pa1 : pa0;
        f32x4 qa[4];
#pragma unroll
        for (int nt = 0; nt < 4; ++nt)
            qa[nt] = __builtin_amdgcn_mfma_f32_16x16x32_f16(
                pa.h, phif[nt].h, (f32x4){0.f, 0.f, 0.f, 0.f}, 0, 0, 0);
#pragma unroll
        for (int nt = 0; nt < 4; ++nt) {
            float a0 = __builtin_amdgcn_exp2f(qa[nt][0]);
            float a1 = __builtin_amdgcn_exp2f(qa[nt][1]);
            float a2 = __builtin_amdgcn_exp2f(qa[nt][2]);
            float a3 = __builtin_amdgcn_exp2f(qa[nt][3]);
            const int row = wv * 64 + nt * 16 + ln;
            const int dbase = row * RSTR + (m * 8 + quad * 2);
            *(uint2v*)&sh[dbase] = (uint2v){pkrtz(a0, a1), pkrtz(a2, a3)};
        }
    }

    // ---- T-chain, quad-factored (R10-verified): cumulative (1-a) products
    // off the T critical path; only T *= p is serial (1 mul per 4 gaussians).
#pragma unroll
    for (int i = 0; i < 4; ++i) {
        uint4v a4 = *(const uint4v*)&sh[ridx(tid, i)];
        uint4v w4;
#pragma unroll
        for (int h = 0; h < 2; ++h) {
            H2U u0; u0.u = a4[2 * h + 0];
            H2U u1; u1.u = a4[2 * h + 1];
            float a0 = (float)u0.h[0];
            float a1 = (float)u0.h[1];
            float a2 = (float)u1.h[0];
            float a3 = (float)u1.h[1];
            float c1 = 1.0f - a0;
            float t1 = c1 * a1; float c2 = c1 - t1;
            float t2 = c2 * a2; float c3 = c2 - t2;
            float t3 = c3 * a3; float pq = c3 - t3;
            float w0 = T * a0;
            float w1 = T * t1;
            float w2 = T * t2;
            float w3 = T * t3;
            T = T * pq;
            w4[2 * h + 0] = pkrtz(w0, w1);
            w4[2 * h + 1] = pkrtz(w2, w3);
        }
        *(uint4v*)&sh[ridx(tid, i)] = w4;
    }

    // ---- PV GEMM (R6+-verified path)
#pragma unroll
    for (int mt = 0; mt < 4; ++mt) {
        FRAG af;
        af.v = *(const uint4v*)&sh[ridx(wv * 64 + mt * 16 + ln, quad)];
        pvacc[mt][0] = __builtin_amdgcn_mfma_f32_16x16x32_f16(af.h, bf0.h, pvacc[mt][0], 0, 0, 0);
        pvacc[mt][1] = __builtin_amdgcn_mfma_f32_16x16x32_f16(af.h, bf1.h, pvacc[mt][1], 0, 0, 0);
    }
}

// ---------------------------------------------------------------------------
// gr_render R13: 64 points/block, 8 waves = 8 gaussian segments of 64.
// Same total work per block as R12 (64 chunk-instances) but 2x the waves and
// half the per-wave serial chain -> latency-bound kernel gets 2.7x TLP.
// LDS = 512 rows x 80 B = 40960 B exactly -> 4 blocks/CU (32 waves, 100%).
// tT folded into spare dword 16 of each row.
// ---------------------------------------------------------------------------
__global__ __launch_bounds__(512, 8) void gr_render(
    const unsigned* __restrict__ psi,
    const unsigned* __restrict__ ftg,
    const float* __restrict__ coords,
    float* __restrict__ out)
{
    __shared__ uint4v sh4[TPB * 5];          // 40960 B: [512 rows][20 dw]
    unsigned* sh = (unsigned*)sh4;

    const int tid  = threadIdx.x;
    const int ln   = tid & 15;
    const int quad = (tid >> 4) & 3;
    const int wv   = tid >> 6;               // 0..7: gaussian segment
    const int lane = tid & 63;

    const int p = blockIdx.x * PTS + lane;   // this lane's point
    const float cx = coords[p * 3 + 0];
    const float cy = coords[p * 3 + 1];
    const float cz = coords[p * 3 + 2];

    // ---- prologue: issue chunk 0's A-frag loads; latency hides under the
    // phi' setup + LDS round-trip below.
    const int c0 = wv * CPS;                 // 2 chunks per segment
    FRAG paA0, paA1, paB0, paB1;
    paA0.v = ((const uint4v*)(psi + (2 * c0 + 0) * 256))[lane];
    paA1.v = ((const uint4v*)(psi + (2 * c0 + 1) * 256))[lane];

    // ---- phi' (hi/lo split) -> own wave's LDS rows -> B-frags (R7-verified)
    {
        float ph[10] = {cx * cx, cy * cy, cz * cz, cx * cy, cx * cz, cy * cz,
                        cx, cy, cz, 1.0f};
        __fp16 s[32];
#pragma unroll
        for (int i = 0; i < 10; ++i) {
            __fp16 hi = (__fp16)ph[i];
            __fp16 lo = (__fp16)(ph[i] - (float)hi);
            s[i] = hi; s[10 + i] = hi; s[20 + i] = lo;
        }
        s[30] = (__fp16)0.f; s[31] = (__fp16)0.f;
#pragma unroll
        for (int i = 0; i < 4; ++i) {
            uint4v v = (uint4v){packh(s[8 * i + 0], s[8 * i + 1]),
                                packh(s[8 * i + 2], s[8 * i + 3]),
                                packh(s[8 * i + 4], s[8 * i + 5]),
                                packh(s[8 * i + 6], s[8 * i + 7])};
            *(uint4v*)&sh[ridx(tid, i)] = v;
        }
    }

    FRAG phif[4];
#pragma unroll
    for (int nt = 0; nt < 4; ++nt)
        phif[nt].v = *(const uint4v*)&sh[ridx(wv * 64 + nt * 16 + ln, quad)];

    f32x4 pvacc[4][2];
#pragma unroll
    for (int mt = 0; mt < 4; ++mt) {
        pvacc[mt][0] = (f32x4){0.f, 0.f, 0.f, 0.f};
        pvacc[mt][1] = (f32x4){0.f, 0.f, 0.f, 0.f};
    }
    float T = 1.0f;

    // ---- 2 chunks, manually unrolled with rotated A-frag register sets
    gr_chunk(psi, ftg, sh, c0 + 0, c0 + 1, true,  tid, ln, quad, wv, lane,
             phif, pvacc, T, paA0, paA1, paB0, paB1);
    gr_chunk(psi, ftg, sh, c0 + 1, 0,      false, tid, ln, quad, wv, lane,
             phif, pvacc, T, paB0, paB1, paA0, paA1);

    // ---- write segment partials (f16 feature-pairs) into own rows; dword d
    // of row p holds features (d, d+16). tT -> spare dword 16 of own row.
    sh[(wv * 64 + lane) * RSTR + 16] = __float_as_uint(T);
#pragma unroll
    for (int mt = 0; mt < 4; ++mt)
#pragma unroll
        for (int r = 0; r < 4; ++r)
            sh[(wv * 64 + mt * 16 + quad * 4 + r) * RSTR + ln] =
                pkrtz(pvacc[mt][0][r], pvacc[mt][1][r]);

    __syncthreads();

    // ---- compose segments: out = sum_s (prod_{s'<s} T_s') * acc_s
    if (tid < 256) {
        const int pp = tid >> 2;        // point 0..63
        const int g  = tid & 3;         // dword group (4 dwords)

        float o[8];
#pragma unroll
        for (int j = 0; j < 8; ++j) o[j] = 0.f;
        float w = 1.0f;
#pragma unroll
        for (int s = 0; s < NSEG; ++s) {
            uint4v v = *(const uint4v*)&sh[(s * 64 + pp) * RSTR + g * 4];
            float ts = __uint_as_float(sh[(s * 64 + pp) * RSTR + 16]);
#pragma unroll
            for (int j = 0; j < 4; ++j) {
                H2U u; u.u = v[j];
                o[j]     = fmaf(w, (float)u.h[0], o[j]);
                o[4 + j] = fmaf(w, (float)u.h[1], o[4 + j]);
            }
            w *= ts;
        }

        float* __restrict__ ob = out + (blockIdx.x * PTS + pp) * NF + g * 4;
        *(float4*)ob        = make_float4(o[0], o[1], o[2], o[3]);
        *(float4*)(ob + 16) = make_float4(o[4], o[5], o[6], o[7]);
    }
}

extern "C" void kernel_launch(void* const* d_in, const int* in_sizes, int n_in,
                              void* d_out, int out_size, void* d_ws, size_t ws_size,
                              hipStream_t stream)
{
    const float* means  = (const float*)d_in[0];   // (512,3)
    const float* scales = (const float*)d_in[1];   // (512,3)
    const float* rots   = (const float*)d_in[2];   // (512,4)
    const float* opac   = (const float*)d_in[3];   // (512,1)
    const float* feats  = (const float*)d_in[4];   // (512,32)
    const float* cam    = (const float*)d_in[5];   // (4,4)
    const float* coords = (const float*)d_in[6];   // (96,96,16,3)
    float* out = (float*)d_out;                    // (96,96,16,32) fp32

    unsigned* psi = (unsigned*)d_ws;               // 32 KiB: gaussian A-frag image
    unsigned* ftg = psi + 32 * 256;                // 32 KiB: feats B-frag image

    gr_pack<<<34, 256, 0, stream>>>(means, scales, rots, opac, cam, feats, psi, ftg);
    gr_render<<<NP / PTS, TPB, 0, stream>>>(psi, ftg, coords, out);
}

// Round 7
// 94.024 us; speedup vs baseline: 1.1956x; 1.0259x over previous
//
#include <hip/hip_runtime.h>

#define NG 512
#define NF 32
#define NP (96 * 96 * 16)   // 147456 points
#define TPB 512             // R13: 8 waves; 64 points per block, 8 gaussian segments
#define PTS 64
#define NSEG 8
#define CPS 2               // chunks (of 32 gaussians) per segment
#define RSTR 20             // R12: LDS row stride in dwords (80 B). 5 coprime
                            // to 8 -> bank base 4*((5*row+grp)%8) spreads all
                            // 32 banks (stride 16 locked b128s to 16 banks).

typedef _Float16 half8 __attribute__((ext_vector_type(8)));
typedef __fp16  fp16x2 __attribute__((ext_vector_type(2)));
typedef float f32x4 __attribute__((ext_vector_type(4)));
typedef unsigned uint4v __attribute__((ext_vector_type(4)));
typedef unsigned uint2v __attribute__((ext_vector_type(2)));

union H2U { fp16x2 h; unsigned u; };
union FRAG { unsigned u[4]; uint4v v; half8 h; };

__device__ __forceinline__ unsigned packh(__fp16 a, __fp16 b) {
    H2U p; p.h = (fp16x2){a, b}; return p.u;
}
__device__ __forceinline__ unsigned pkrtz(float a, float b) {
    H2U p; p.h = __builtin_amdgcn_cvt_pkrtz(a, b); return p.u;
}
// R12: dword index into a [512 rows][20 dw] LDS image, linear in-row slots.
// Dwords 0..15 hold frag data; dword 16 holds the segment transmittance.
__device__ __forceinline__ int ridx(int row, int grp) {
    return row * RSTR + 4 * grp;
}

// ---------------------------------------------------------------------------
// gr_pack (R7+-verified): blocks 0-1 psi A-frag image (hi/lo f16 split,
// MFMA A-operand order); blocks 2-33 feats B-frag image. (Unchanged.)
// ---------------------------------------------------------------------------
__global__ __launch_bounds__(256) void gr_pack(
    const float* __restrict__ means,
    const float* __restrict__ scales,
    const float* __restrict__ rots,
    const float* __restrict__ opac,
    const float* __restrict__ cam,
    const float* __restrict__ feats,
    unsigned* __restrict__ psi,
    unsigned* __restrict__ ftg)
{
    const int b = blockIdx.x;
    const int tid = threadIdx.x;

    if (b < 2) {
        const int n = b * 256 + tid;   // 0..511

        float mx = means[n * 3 + 0];
        float my = means[n * 3 + 1];
        float mz = means[n * 3 + 2];

        float h0 = cam[0]  * mx + cam[1]  * my + cam[2]  * mz + cam[3];
        float h1 = cam[4]  * mx + cam[5]  * my + cam[6]  * mz + cam[7];
        float h2 = cam[8]  * mx + cam[9]  * my + cam[10] * mz + cam[11];
        float h3 = cam[12] * mx + cam[13] * my + cam[14] * mz + cam[15];
        float ih3 = 1.0f / h3;
        mx = h0 * ih3; my = h1 * ih3; mz = h2 * ih3;

        float qw = rots[n * 4 + 0];
        float qx = rots[n * 4 + 1];
        float qy = rots[n * 4 + 2];
        float qz = rots[n * 4 + 3];
        float qinv = 1.0f / sqrtf(qw * qw + qx * qx + qy * qy + qz * qz);
        qw *= qinv; qx *= qinv; qy *= qinv; qz *= qinv;

        float R00 = 1.0f - 2.0f * (qy * qy + qz * qz);
        float R01 = 2.0f * (qx * qy - qw * qz);
        float R02 = 2.0f * (qx * qz + qw * qy);
        float R10 = 2.0f * (qx * qy + qw * qz);
        float R11 = 1.0f - 2.0f * (qx * qx + qz * qz);
        float R12 = 2.0f * (qy * qz - qw * qx);
        float R20 = 2.0f * (qx * qz - qw * qy);
        float R21 = 2.0f * (qy * qz + qw * qx);
        float R22 = 1.0f - 2.0f * (qx * qx + qy * qy);

        float s0 = scales[n * 3 + 0];
        float s1 = scales[n * 3 + 1];
        float s2 = scales[n * 3 + 2];
        const float es = 0.7213475204444817f;   // 0.5*log2(e)
        float i0 = es / (s0 * s0);
        float i1 = es / (s1 * s1);
        float i2 = es / (s2 * s2);

        float a00 = R00 * R00 * i0 + R01 * R01 * i1 + R02 * R02 * i2;
        float a01 = R00 * R10 * i0 + R01 * R11 * i1 + R02 * R12 * i2;
        float a02 = R00 * R20 * i0 + R01 * R21 * i1 + R02 * R22 * i2;
        float a11 = R10 * R10 * i0 + R11 * R11 * i1 + R12 * R12 * i2;
        float a12 = R10 * R20 * i0 + R11 * R21 * i1 + R12 * R22 * i2;
        float a22 = R20 * R20 * i0 + R21 * R21 * i1 + R22 * R22 * i2;

        float amx = a00 * mx + a01 * my + a02 * mz;
        float amy = a01 * mx + a11 * my + a12 * mz;
        float amz = a02 * mx + a12 * my + a22 * mz;

        float psv[10];
        psv[0] = -a00; psv[1] = -a11; psv[2] = -a22;
        psv[3] = -2.0f * a01; psv[4] = -2.0f * a02; psv[5] = -2.0f * a12;
        psv[6] = 2.0f * amx; psv[7] = 2.0f * amy; psv[8] = 2.0f * amz;
        psv[9] = __log2f(opac[n]) - (mx * amx + my * amy + mz * amz);

        __fp16 s[32];
#pragma unroll
        for (int i = 0; i < 10; ++i) {
            __fp16 hi = (__fp16)psv[i];
            __fp16 lo = (__fp16)(psv[i] - (float)hi);
            s[i] = hi; s[10 + i] = lo; s[20 + i] = hi;
        }
        s[30] = (__fp16)0.f; s[31] = (__fp16)0.f;

        unsigned* base = psi + (n >> 4) * 256;
        const int lr = n & 15;
#pragma unroll
        for (int q = 0; q < 4; ++q)
#pragma unroll
            for (int jp = 0; jp < 4; ++jp)
                base[(lr + 16 * q) * 4 + jp] = packh(s[8 * q + 2 * jp], s[8 * q + 2 * jp + 1]);
    } else {
        int d = (b - 2) * 256 + tid;   // 0..8191
        int c  = d >> 9;
        int r  = d & 511;
        int nt = r >> 8;
        int l  = (r >> 2) & 63;
        int jp = r & 3;
        int n  = nt * 16 + (l & 15);
        int k0 = c * 32 + (l >> 4) * 8 + 2 * jp;
        ftg[d] = pkrtz(feats[k0 * NF + n], feats[(k0 + 1) * NF + n]);
    }
}

// ---------------------------------------------------------------------------
// Chunk body (R10/R12-verified math, bit-identical). R14 register diet:
// (1) R11 prefetch REMOVED (twice-measured neutral; 8-wave TLP covers the
//     chunk-top vmcnt) -> frees 16 VGPRs;
// (2) exp2+store folded into the per-nt loop (qa liveness 16 -> 4 regs;
//     the per-nt MFMA->VALU stall is covered by TLP).
// Goal: peak live ~78 regs so __launch_bounds__(512,6) allocates w/o spill.
// ---------------------------------------------------------------------------
__device__ __forceinline__ void gr_chunk(
    const unsigned* __restrict__ psi,
    const unsigned* __restrict__ ftg,
    unsigned* sh,
    int c,
    int tid, int ln, int quad, int wv, int lane,
    const FRAG (&phif)[4], f32x4 (&pvacc)[4][2], float& T)
{
    // ---- VMEM: this chunk's A- and B-frags, one issue burst
    FRAG pa0, pa1, bf0, bf1;
    pa0.v = ((const uint4v*)(psi + (2 * c + 0) * 256))[lane];
    pa1.v = ((const uint4v*)(psi + (2 * c + 1) * 256))[lane];
    bf0.v = ((const uint4v*)(ftg + c * 512 + 0))[lane];
    bf1.v = ((const uint4v*)(ftg + c * 512 + 256))[lane];

    // ---- Q GEMM + exp2, per nt (minimal qa liveness)
#pragma unroll
    for (int m = 0; m < 2; ++m) {
        const FRAG& pa = m ? pa1 : pa0;
#pragma unroll
        for (int nt = 0; nt < 4; ++nt) {
            f32x4 qa = __builtin_amdgcn_mfma_f32_16x16x32_f16(
                pa.h, phif[nt].h, (f32x4){0.f, 0.f, 0.f, 0.f}, 0, 0, 0);
            float a0 = __builtin_amdgcn_exp2f(qa[0]);
            float a1 = __builtin_amdgcn_exp2f(qa[1]);
            float a2 = __builtin_amdgcn_exp2f(qa[2]);
            float a3 = __builtin_amdgcn_exp2f(qa[3]);
            const int row = wv * 64 + nt * 16 + ln;
            const int dbase = row * RSTR + (m * 8 + quad * 2);
            *(uint2v*)&sh[dbase] = (uint2v){pkrtz(a0, a1), pkrtz(a2, a3)};
        }
    }

    // ---- T-chain, quad-factored (R10-verified): cumulative (1-a) products
    // off the T critical path; only T *= p is serial (1 mul per 4 gaussians).
#pragma unroll
    for (int i = 0; i < 4; ++i) {
        uint4v a4 = *(const uint4v*)&sh[ridx(tid, i)];
        uint4v w4;
#pragma unroll
        for (int h = 0; h < 2; ++h) {
            H2U u0; u0.u = a4[2 * h + 0];
            H2U u1; u1.u = a4[2 * h + 1];
            float a0 = (float)u0.h[0];
            float a1 = (float)u0.h[1];
            float a2 = (float)u1.h[0];
            float a3 = (float)u1.h[1];
            float c1 = 1.0f - a0;
            float t1 = c1 * a1; float c2 = c1 - t1;
            float t2 = c2 * a2; float c3 = c2 - t2;
            float t3 = c3 * a3; float pq = c3 - t3;
            float w0 = T * a0;
            float w1 = T * t1;
            float w2 = T * t2;
            float w3 = T * t3;
            T = T * pq;
            w4[2 * h + 0] = pkrtz(w0, w1);
            w4[2 * h + 1] = pkrtz(w2, w3);
        }
        *(uint4v*)&sh[ridx(tid, i)] = w4;
    }

    // ---- PV GEMM (R6+-verified path)
#pragma unroll
    for (int mt = 0; mt < 4; ++mt) {
        FRAG af;
        af.v = *(const uint4v*)&sh[ridx(wv * 64 + mt * 16 + ln, quad)];
        pvacc[mt][0] = __builtin_amdgcn_mfma_f32_16x16x32_f16(af.h, bf0.h, pvacc[mt][0], 0, 0, 0);
        pvacc[mt][1] = __builtin_amdgcn_mfma_f32_16x16x32_f16(af.h, bf1.h, pvacc[mt][1], 0, 0, 0);
    }
}

// ---------------------------------------------------------------------------
// gr_render R14: 64 points/block, 8 waves = 8 gaussian segments of 64.
// __launch_bounds__(512,6): ~85-reg cap fits the dieted per-wave state
// (pvacc 32 + phif 16 + pa 8 + bf 8 + temps) WITHOUT spilling -> 3 blocks/CU
// (24 waves, 75%) vs R13's forced-8/EU which demanded ~80 regs under a
// 64-reg cap and likely spilled to scratch.
// LDS = 512 rows x 80 B = 40960 B; tT folded into spare dword 16.
// ---------------------------------------------------------------------------
__global__ __launch_bounds__(512, 6) void gr_render(
    const unsigned* __restrict__ psi,
    const unsigned* __restrict__ ftg,
    const float* __restrict__ coords,
    float* __restrict__ out)
{
    __shared__ uint4v sh4[TPB * 5];          // 40960 B: [512 rows][20 dw]
    unsigned* sh = (unsigned*)sh4;

    const int tid  = threadIdx.x;
    const int ln   = tid & 15;
    const int quad = (tid >> 4) & 3;
    const int wv   = tid >> 6;               // 0..7: gaussian segment
    const int lane = tid & 63;

    const int p = blockIdx.x * PTS + lane;   // this lane's point
    const float cx = coords[p * 3 + 0];
    const float cy = coords[p * 3 + 1];
    const float cz = coords[p * 3 + 2];

    // ---- phi' (hi/lo split) -> own wave's LDS rows -> B-frags (R7-verified)
    {
        float ph[10] = {cx * cx, cy * cy, cz * cz, cx * cy, cx * cz, cy * cz,
                        cx, cy, cz, 1.0f};
        __fp16 s[32];
#pragma unroll
        for (int i = 0; i < 10; ++i) {
            __fp16 hi = (__fp16)ph[i];
            __fp16 lo = (__fp16)(ph[i] - (float)hi);
            s[i] = hi; s[10 + i] = hi; s[20 + i] = lo;
        }
        s[30] = (__fp16)0.f; s[31] = (__fp16)0.f;
#pragma unroll
        for (int i = 0; i < 4; ++i) {
            uint4v v = (uint4v){packh(s[8 * i + 0], s[8 * i + 1]),
                                packh(s[8 * i + 2], s[8 * i + 3]),
                                packh(s[8 * i + 4], s[8 * i + 5]),
                                packh(s[8 * i + 6], s[8 * i + 7])};
            *(uint4v*)&sh[ridx(tid, i)] = v;
        }
    }

    FRAG phif[4];
#pragma unroll
    for (int nt = 0; nt < 4; ++nt)
        phif[nt].v = *(const uint4v*)&sh[ridx(wv * 64 + nt * 16 + ln, quad)];

    f32x4 pvacc[4][2];
#pragma unroll
    for (int mt = 0; mt < 4; ++mt) {
        pvacc[mt][0] = (f32x4){0.f, 0.f, 0.f, 0.f};
        pvacc[mt][1] = (f32x4){0.f, 0.f, 0.f, 0.f};
    }
    float T = 1.0f;

    // ---- 2 chunks per segment
    const int c0 = wv * CPS;
    gr_chunk(psi, ftg, sh, c0 + 0, tid, ln, quad, wv, lane, phif, pvacc, T);
    gr_chunk(psi, ftg, sh, c0 + 1, tid, ln, quad, wv, lane, phif, pvacc, T);

    // ---- write segment partials (f16 feature-pairs) into own rows; dword d
    // of row p holds features (d, d+16). tT -> spare dword 16 of own row.
    sh[(wv * 64 + lane) * RSTR + 16] = __float_as_uint(T);
#pragma unroll
    for (int mt = 0; mt < 4; ++mt)
#pragma unroll
        for (int r = 0; r < 4; ++r)
            sh[(wv * 64 + mt * 16 + quad * 4 + r) * RSTR + ln] =
                pkrtz(pvacc[mt][0][r], pvacc[mt][1][r]);

    __syncthreads();

    // ---- compose segments: out = sum_s (prod_{s'<s} T_s') * acc_s
    if (tid < 256) {
        const int pp = tid >> 2;        // point 0..63
        const int g  = tid & 3;         // dword group (4 dwords)

        float o[8];
#pragma unroll
        for (int j = 0; j < 8; ++j) o[j] = 0.f;
        float w = 1.0f;
#pragma unroll
        for (int s = 0; s < NSEG; ++s) {
            uint4v v = *(const uint4v*)&sh[(s * 64 + pp) * RSTR + g * 4];
            float ts = __uint_as_float(sh[(s * 64 + pp) * RSTR + 16]);
#pragma unroll
            for (int j = 0; j < 4; ++j) {
                H2U u; u.u = v[j];
                o[j]     = fmaf(w, (float)u.h[0], o[j]);
                o[4 + j] = fmaf(w, (float)u.h[1], o[4 + j]);
            }
            w *= ts;
        }

        float* __restrict__ ob = out + (blockIdx.x * PTS + pp) * NF + g * 4;
        *(float4*)ob        = make_float4(o[0], o[1], o[2], o[3]);
        *(float4*)(ob + 16) = make_float4(o[4], o[5], o[6], o[7]);
    }
}

extern "C" void kernel_launch(void* const* d_in, const int* in_sizes, int n_in,
                              void* d_out, int out_size, void* d_ws, size_t ws_size,
                              hipStream_t stream)
{
    const float* means  = (const float*)d_in[0];   // (512,3)
    const float* scales = (const float*)d_in[1];   // (512,3)
    const float* rots   = (const float*)d_in[2];   // (512,4)
    const float* opac   = (const float*)d_in[3];   // (512,1)
    const float* feats  = (const float*)d_in[4];   // (512,32)
    const float* cam    = (const float*)d_in[5];   // (4,4)
    const float* coords = (const float*)d_in[6];   // (96,96,16,3)
    float* out = (float*)d_out;                    // (96,96,16,32) fp32

    unsigned* psi = (unsigned*)d_ws;               // 32 KiB: gaussian A-frag image
    unsigned* ftg = psi + 32 * 256;                // 32 KiB: feats B-frag image

    gr_pack<<<34, 256, 0, stream>>>(means, scales, rots, opac, cam, feats, psi, ftg);
    gr_render<<<NP / PTS, TPB, 0, stream>>>(psi, ftg, coords, out);
}